// Round 6
// baseline (2182.261 us; speedup 1.0000x reference)
//
#include <hip/hip_runtime.h>
#include <math.h>

#define NN 100000
#define NE 1600000
#define D 64
#define NG 2000
#define LN_EPS 1e-5f
#define NB ((NN + 255) / 256)        // 391 buckets of 256 nodes
#define NBK NB
#define EPB 6400                     // edges per partition block (250 blocks)
#define NPART (NE / EPB)             // 250
#define CAP 6144                     // bucket capacity (expected 4096, ~32 sigma slack)
#define ASTR 68                      // padded f32 accumulator row stride
#define LSTR 72                      // padded LDS row stride (shorts), 144B = 9*16
#define WFRAG_MLP 24576              // 3 layers * 2 mats * 4096
#define WFRAG_TOT 26624              // + gate 2048
#define CONV1K ((NN * D) / 1024)     // 6250
#define WPREP1K (WFRAG_TOT / 1024)   // 26

typedef __attribute__((ext_vector_type(8))) short short8;            // 8 bf16 in 4 VGPRs
typedef __attribute__((ext_vector_type(8))) unsigned short ushort8;  // 16B row slice
typedef __attribute__((ext_vector_type(4))) float floatx4;           // MFMA accumulator

__device__ __forceinline__ unsigned short f2bf(float f) {
    unsigned int u = __float_as_uint(f);
    u += 0x7FFF + ((u >> 16) & 1);   // round-to-nearest-even
    return (unsigned short)(u >> 16);
}
__device__ __forceinline__ float bfu2f(unsigned short v) {
    return __uint_as_float(((unsigned int)v) << 16);
}

// ========== fused prep+partition: [part blocks | x->bf16 conv | weight frag] ==========
__global__ __launch_bounds__(1024) void k_prep_part(const float* __restrict__ x,
                                                    unsigned short* __restrict__ xb,
                                                    const float* __restrict__ W1,
                                                    const float* __restrict__ W2,
                                                    const float* __restrict__ gw1,
                                                    unsigned short* __restrict__ wfrag,
                                                    const int* __restrict__ src,
                                                    const int* __restrict__ dst,
                                                    int* __restrict__ bcur,
                                                    unsigned int* __restrict__ colbuf) {
    __shared__ int lcnt[NBK];
    __shared__ int lbase[NBK];
    int b = blockIdx.x;
    int tid = threadIdx.x;

    if (b < NPART) {
        int e0 = b * EPB;
        for (int i = tid; i < NBK; i += 1024) lcnt[i] = 0;
        __syncthreads();

        for (int e = tid; e < EPB; e += 1024)
            atomicAdd(&lcnt[dst[e0 + e] >> 8], 1);
        __syncthreads();

        for (int i = tid; i < NBK; i += 1024) {
            int c = lcnt[i];
            lbase[i] = c ? (i * CAP + atomicAdd(&bcur[i * 16], c)) : 0;
            lcnt[i] = 0;
        }
        __syncthreads();

        for (int e = tid; e < EPB; e += 1024) {
            int d = dst[e0 + e];
            int s = src[e0 + e];
            int bk = d >> 8;
            int pos = lbase[bk] + atomicAdd(&lcnt[bk], 1);
            colbuf[pos] = ((unsigned int)s << 8) | (unsigned int)(d & 255);
        }
    } else if (b < NPART + CONV1K) {
        int i = (b - NPART) * 1024 + tid;
        xb[i] = f2bf(x[i]);
    } else {
        int idx = (b - NPART - CONV1K) * 1024 + tid;
        if (idx < WFRAG_MLP) {
            int l = idx / 8192;
            int rem = idx % 8192;
            int mat = rem / 4096;
            int r2 = rem % 4096;
            int ks = r2 / 2048;
            int c = (r2 / 512) % 4;
            int lane = (r2 / 8) % 64;
            int j = r2 % 8;
            int n = lane & 15, q = lane >> 4;
            int k = ks * 32 + q * 8 + j;
            int col = c * 16 + n;
            const float* Wm = mat ? W2 : W1;
            wfrag[idx] = f2bf(Wm[l * 4096 + k * 64 + col]);
        } else {
            int g = idx - WFRAG_MLP;
            int ks = g / 1024;
            int c = (g / 512) % 2;
            int lane = (g / 8) % 64;
            int j = g % 8;
            int n = lane & 15, q = lane >> 4;
            int k = ks * 32 + q * 8 + j;
            wfrag[idx] = f2bf(gw1[k * 32 + c * 16 + n]);
        }
    }
}

// ================= fused layer: LDS-atomic gather + MFMA MLP + LN (+gate) =================
// block = half-bucket (128 nodes), 512 threads / 8 waves.
// phase 0: acc[128][68] f32 = (1+eps)*x
// phase 1: scan the bucket's unsorted tagged edge segment; 8-lane groups load src rows
//          (16B/lane, 8 edges in flight) and ds_add_f32 into acc (perfectly balanced)
// phase 2: 8 waves x one 16-node MFMA tile each (no idle waves)
template <int LAST>
__global__ __launch_bounds__(512, 4) void k_layer(const unsigned short* __restrict__ xin,
                                                  unsigned short* __restrict__ xout,
                                                  const unsigned int* __restrict__ colbuf,
                                                  const int* __restrict__ bcur,
                                                  const float* __restrict__ epsp,
                                                  const short8* __restrict__ wf,
                                                  const short8* __restrict__ gf,
                                                  const float* __restrict__ b1,
                                                  const float* __restrict__ b2,
                                                  const float* __restrict__ lng,
                                                  const float* __restrict__ lnb,
                                                  const float* __restrict__ gb1,
                                                  const float* __restrict__ gw2,
                                                  const float* __restrict__ gb2,
                                                  float* __restrict__ gate) {
    __shared__ __align__(16) float acc[128 * ASTR];              // 34.8 KB
    __shared__ __align__(16) unsigned short smA[8][16 * LSTR];   // 18.4 KB
    int b = blockIdx.x >> 1;
    int half = blockIdx.x & 1;
    int tid = threadIdx.x;
    int w = tid >> 6;
    int lane = tid & 63;
    int g = lane >> 3;
    int fl = lane & 7;
    int nodebase = b * 256 + half * 128;
    float ev = 1.0f + *epsp;

    // ---- phase 0: init acc = (1+eps)*x ----
    {
        int r = tid >> 2;             // 0..127
        int c16 = (tid & 3) * 16;     // 16-float chunk
        int node = nodebase + r;
        float4 o0 = {0, 0, 0, 0}, o1 = o0, o2 = o0, o3 = o0;
        if (node < NN) {
            const ushort8* xp = (const ushort8*)(xin + ((size_t)node << 6) + c16);
            ushort8 u0 = xp[0], u1 = xp[1];
            o0 = {ev * bfu2f(u0[0]), ev * bfu2f(u0[1]), ev * bfu2f(u0[2]), ev * bfu2f(u0[3])};
            o1 = {ev * bfu2f(u0[4]), ev * bfu2f(u0[5]), ev * bfu2f(u0[6]), ev * bfu2f(u0[7])};
            o2 = {ev * bfu2f(u1[0]), ev * bfu2f(u1[1]), ev * bfu2f(u1[2]), ev * bfu2f(u1[3])};
            o3 = {ev * bfu2f(u1[4]), ev * bfu2f(u1[5]), ev * bfu2f(u1[6]), ev * bfu2f(u1[7])};
        }
        float* ap = acc + r * ASTR + c16;
        *(float4*)(ap + 0) = o0;
        *(float4*)(ap + 4) = o1;
        *(float4*)(ap + 8) = o2;
        *(float4*)(ap + 12) = o3;
    }
    __syncthreads();

    // ---- phase 1: edge-balanced scatter via LDS atomic f32 ----
    {
        int cnt = bcur[b * 16];
        const unsigned int* cb = colbuf + (size_t)b * CAP;
        for (int sp = 0; sp < cnt; sp += 512) {
            int myE = sp + w * 64 + lane;
            unsigned int tag = (myE < cnt) ? cb[myE] : 0xFFFFFFFFu;
            ushort8 v[8];
            int dl[8];
            unsigned int vmask = 0;
#pragma unroll
            for (int k = 0; k < 8; k++) {
                unsigned int p = __shfl(tag, k * 8 + g, 64);
                int d = p & 255;
                bool val = (p != 0xFFFFFFFFu) && ((d >> 7) == half);
                dl[k] = d & 127;
                if (val) {
                    v[k] = *(const ushort8*)(xin + ((size_t)(p >> 8) << 6) + fl * 8);
                    vmask |= 1u << k;
                }
            }
#pragma unroll
            for (int k = 0; k < 8; k++) {
                if (vmask & (1u << k)) {
                    float* ap = acc + dl[k] * ASTR + fl * 8;
                    atomicAdd(ap + 0, bfu2f(v[k][0]));
                    atomicAdd(ap + 1, bfu2f(v[k][1]));
                    atomicAdd(ap + 2, bfu2f(v[k][2]));
                    atomicAdd(ap + 3, bfu2f(v[k][3]));
                    atomicAdd(ap + 4, bfu2f(v[k][4]));
                    atomicAdd(ap + 5, bfu2f(v[k][5]));
                    atomicAdd(ap + 6, bfu2f(v[k][6]));
                    atomicAdd(ap + 7, bfu2f(v[k][7]));
                }
            }
        }
    }
    __syncthreads();

    // ---- phase 2: MFMA MLP + LN (+gate); wave w owns tile of 16 nodes ----
    int n = lane & 15;
    int q = lane >> 4;
    int base = nodebase + w * 16;

    // A fragments from f32 accumulator
    const float* arow = acc + (w * 16 + n) * ASTR;
    float4 f0 = *(const float4*)(arow + q * 8);
    float4 f1 = *(const float4*)(arow + q * 8 + 4);
    float4 f2 = *(const float4*)(arow + 32 + q * 8);
    float4 f3 = *(const float4*)(arow + 32 + q * 8 + 4);
    short8 A0, A1;
    A0[0] = (short)f2bf(f0.x); A0[1] = (short)f2bf(f0.y);
    A0[2] = (short)f2bf(f0.z); A0[3] = (short)f2bf(f0.w);
    A0[4] = (short)f2bf(f1.x); A0[5] = (short)f2bf(f1.y);
    A0[6] = (short)f2bf(f1.z); A0[7] = (short)f2bf(f1.w);
    A1[0] = (short)f2bf(f2.x); A1[1] = (short)f2bf(f2.y);
    A1[2] = (short)f2bf(f2.z); A1[3] = (short)f2bf(f2.w);
    A1[4] = (short)f2bf(f3.x); A1[5] = (short)f2bf(f3.y);
    A1[6] = (short)f2bf(f3.z); A1[7] = (short)f2bf(f3.w);

    short8 B1f[2][4], B2f[2][4];
#pragma unroll
    for (int ks = 0; ks < 2; ks++)
#pragma unroll
        for (int c = 0; c < 4; c++) {
            B1f[ks][c] = wf[(ks * 4 + c) * 64 + lane];
            B2f[ks][c] = wf[512 + (ks * 4 + c) * 64 + lane];
        }
    short8 B3f[2][2];
    if (LAST) {
#pragma unroll
        for (int ks = 0; ks < 2; ks++)
#pragma unroll
            for (int c = 0; c < 2; c++)
                B3f[ks][c] = gf[(ks * 2 + c) * 64 + lane];
    }

    float b1v[4], b2v[4], lgv[4], lbv[4];
#pragma unroll
    for (int c = 0; c < 4; c++) {
        b1v[c] = b1[c * 16 + n];
        b2v[c] = b2[c * 16 + n];
        lgv[c] = lng[c * 16 + n];
        lbv[c] = lnb[c * 16 + n];
    }
    float gb1v[2], gw2v[2], gb2v = 0.f;
    if (LAST) {
        gb1v[0] = gb1[n]; gb1v[1] = gb1[16 + n];
        gw2v[0] = gw2[n]; gw2v[1] = gw2[16 + n];
        gb2v = gb2[0];
    }

    unsigned short* aw = smA[w];

    floatx4 acc1[4];
#pragma unroll
    for (int c = 0; c < 4; c++) {
        floatx4 a = {b1v[c], b1v[c], b1v[c], b1v[c]};
        a = __builtin_amdgcn_mfma_f32_16x16x32_bf16(A0, B1f[0][c], a, 0, 0, 0);
        a = __builtin_amdgcn_mfma_f32_16x16x32_bf16(A1, B1f[1][c], a, 0, 0, 0);
        acc1[c] = a;
    }

#pragma unroll
    for (int c = 0; c < 4; c++)
#pragma unroll
        for (int r = 0; r < 4; r++) {
            float v = acc1[c][r];
            v = v / (1.0f + __expf(-v));
            aw[(q * 4 + r) * LSTR + c * 16 + n] = f2bf(v);
        }

    const short8* ap = (const short8*)(aw + n * LSTR);
    short8 A20 = ap[q];
    short8 A21 = ap[4 + q];

    floatx4 acc2[4];
#pragma unroll
    for (int c = 0; c < 4; c++) {
        floatx4 a = {b2v[c], b2v[c], b2v[c], b2v[c]};
        a = __builtin_amdgcn_mfma_f32_16x16x32_bf16(A20, B2f[0][c], a, 0, 0, 0);
        a = __builtin_amdgcn_mfma_f32_16x16x32_bf16(A21, B2f[1][c], a, 0, 0, 0);
        acc2[c] = a;
    }

    float mu[4], inv[4];
#pragma unroll
    for (int r = 0; r < 4; r++) {
        float s = acc2[0][r] + acc2[1][r] + acc2[2][r] + acc2[3][r];
#pragma unroll
        for (int off = 1; off < 16; off <<= 1) s += __shfl_xor(s, off, 64);
        mu[r] = s * (1.0f / 64.0f);
        float d0 = acc2[0][r] - mu[r], d1 = acc2[1][r] - mu[r];
        float d2 = acc2[2][r] - mu[r], d3 = acc2[3][r] - mu[r];
        float vv = d0 * d0 + d1 * d1 + d2 * d2 + d3 * d3;
#pragma unroll
        for (int off = 1; off < 16; off <<= 1) vv += __shfl_xor(vv, off, 64);
        inv[r] = rsqrtf(vv * (1.0f / 64.0f) + LN_EPS);
    }

#pragma unroll
    for (int c = 0; c < 4; c++)
#pragma unroll
        for (int r = 0; r < 4; r++) {
            int onode = base + q * 4 + r;
            float o = (acc2[c][r] - mu[r]) * inv[r] * lgv[c] + lbv[c];
            unsigned short ob = f2bf(o);
            if (onode < NN) xout[((size_t)onode << 6) + c * 16 + n] = ob;
            if (LAST) aw[(q * 4 + r) * LSTR + c * 16 + n] = ob;
        }

    if (LAST) {
        short8 G0 = ap[q];
        short8 G1 = ap[4 + q];
        floatx4 acc3[2];
#pragma unroll
        for (int c = 0; c < 2; c++) {
            floatx4 a = {gb1v[c], gb1v[c], gb1v[c], gb1v[c]};
            a = __builtin_amdgcn_mfma_f32_16x16x32_bf16(G0, B3f[0][c], a, 0, 0, 0);
            a = __builtin_amdgcn_mfma_f32_16x16x32_bf16(G1, B3f[1][c], a, 0, 0, 0);
            acc3[c] = a;
        }
#pragma unroll
        for (int r = 0; r < 4; r++) {
            float v0 = acc3[0][r];
            v0 = v0 / (1.0f + __expf(-v0));
            float v1 = acc3[1][r];
            v1 = v1 / (1.0f + __expf(-v1));
            float gsum = v0 * gw2v[0] + v1 * gw2v[1];
#pragma unroll
            for (int off = 1; off < 16; off <<= 1) gsum += __shfl_xor(gsum, off, 64);
            int onode = base + q * 4 + r;
            if (n == 0 && onode < NN) gate[onode] = gsum + gb2v;
        }
    }
}

// ================= per-graph softmax pooling =================
__global__ __launch_bounds__(256) void k_pool(const unsigned short* __restrict__ xf,
                                              const float* __restrict__ gate,
                                              const int* __restrict__ batch,
                                              float* __restrict__ out) {
    __shared__ float redm[4];
    __shared__ float reds[4];
    __shared__ float racc[4][D];
    int g = blockIdx.x;
    int w = threadIdx.x >> 6;
    int lane = threadIdx.x & 63;

    int lo = 0, hi = NN;
    while (lo < hi) { int mid = (lo + hi) >> 1; if (batch[mid] < g) lo = mid + 1; else hi = mid; }
    int start = lo;
    hi = NN;
    while (lo < hi) { int mid = (lo + hi) >> 1; if (batch[mid] < g + 1) lo = mid + 1; else hi = mid; }
    int end = lo;

    if (start >= end) {
        if (w == 0) out[((size_t)g << 6) + lane] = 0.0f;
        return;
    }

    float m = -INFINITY;
    for (int i = start + (int)threadIdx.x; i < end; i += 256) m = fmaxf(m, gate[i]);
#pragma unroll
    for (int mm = 32; mm >= 1; mm >>= 1) m = fmaxf(m, __shfl_xor(m, mm, 64));
    if (lane == 0) redm[w] = m;
    __syncthreads();
    m = fmaxf(fmaxf(redm[0], redm[1]), fmaxf(redm[2], redm[3]));

    float s = 0.0f;
    for (int i = start + (int)threadIdx.x; i < end; i += 256) s += __expf(gate[i] - m);
#pragma unroll
    for (int mm = 32; mm >= 1; mm >>= 1) s += __shfl_xor(s, mm, 64);
    if (lane == 0) reds[w] = s;
    __syncthreads();
    s = (reds[0] + reds[1]) + (reds[2] + reds[3]);

    float acc = 0.0f;
    for (int i = start + w; i < end; i += 4)
        acc += __expf(gate[i] - m) * bfu2f(xf[((size_t)i << 6) + lane]);
    racc[w][lane] = acc;
    __syncthreads();
    if (w == 0)
        out[((size_t)g << 6) + lane] =
            ((racc[0][lane] + racc[1][lane]) + (racc[2][lane] + racc[3][lane])) / s;
}

extern "C" void kernel_launch(void* const* d_in, const int* in_sizes, int n_in,
                              void* d_out, int out_size, void* d_ws, size_t ws_size,
                              hipStream_t stream) {
    const float* x   = (const float*)d_in[0];
    const int* ei    = (const int*)d_in[1];
    const int* batch = (const int*)d_in[2];
    const float* W1  = (const float*)d_in[3];
    const float* b1  = (const float*)d_in[4];
    const float* W2  = (const float*)d_in[5];
    const float* b2  = (const float*)d_in[6];
    const float* eps = (const float*)d_in[7];
    const float* lng = (const float*)d_in[8];
    const float* lnb = (const float*)d_in[9];
    const float* gw1 = (const float*)d_in[10];
    const float* gb1 = (const float*)d_in[11];
    const float* gw2 = (const float*)d_in[12];
    const float* gb2 = (const float*)d_in[13];

    const int* src = ei;
    const int* dst = ei + NE;

    // workspace layout (~36 MB)
    unsigned short* xb    = (unsigned short*)d_ws;              // NN*64 bf16 (ping)
    unsigned short* h     = xb + (size_t)NN * D;                // NN*64 bf16 (pong)
    float* gate           = (float*)(h + (size_t)NN * D);       // NN f32
    int* colbuf           = (int*)(gate + NN);                  // NBK*CAP (bucketed, tagged)
    int* bcur             = colbuf + (size_t)NBK * CAP;         // NBK*16 counts
    unsigned short* wfrag = (unsigned short*)(bcur + NBK * 16); // WFRAG_TOT

    float* out = (float*)d_out;

    // ---- CSR-lite build + prep (bcur = counts, memset 0; no per-node sort needed) ----
    hipMemsetAsync(bcur, 0, NBK * 16 * sizeof(int), stream);
    k_prep_part<<<NPART + CONV1K + WPREP1K, 1024, 0, stream>>>(
        x, xb, W1, W2, gw1, wfrag, src, dst, bcur, (unsigned int*)colbuf);

    const short8* wf0 = (const short8*)(wfrag);
    const short8* wf1 = (const short8*)(wfrag + 8192);
    const short8* wf2 = (const short8*)(wfrag + 16384);
    const short8* gf  = (const short8*)(wfrag + WFRAG_MLP);

    // ---- 3 fused GIN layers (half-bucket blocks, LDS-atomic aggregation) ----
    k_layer<0><<<NBK * 2, 512, 0, stream>>>(xb, h, (const unsigned int*)colbuf, bcur, eps + 0,
        wf0, gf, b1 + 0 * D, b2 + 0 * D, lng + 0 * D, lnb + 0 * D, gb1, gw2, gb2, gate);

    k_layer<0><<<NBK * 2, 512, 0, stream>>>(h, xb, (const unsigned int*)colbuf, bcur, eps + 1,
        wf1, gf, b1 + 1 * D, b2 + 1 * D, lng + 1 * D, lnb + 1 * D, gb1, gw2, gb2, gate);

    k_layer<1><<<NBK * 2, 512, 0, stream>>>(xb, h, (const unsigned int*)colbuf, bcur, eps + 2,
        wf2, gf, b1 + 2 * D, b2 + 2 * D, lng + 2 * D, lnb + 2 * D, gb1, gw2, gb2, gate);

    k_pool<<<NG, 256, 0, stream>>>(h, gate, batch, out);
}

// Round 7
// 331.897 us; speedup vs baseline: 6.5751x; 6.5751x over previous
//
#include <hip/hip_runtime.h>
#include <math.h>

#define NN 100000
#define NE 1600000
#define D 64
#define NG 2000
#define LN_EPS 1e-5f
#define NB ((NN + 255) / 256)        // 391 buckets of 256 nodes
#define NBK NB
#define NTILE ((NN + 63) / 64)       // 1563
#define EPB 6400                     // edges per partition block (250 blocks)
#define NPART (NE / EPB)             // 250
#define CAP 6144                     // bucket capacity (expected 4096, ~32 sigma slack)
#define LSTR 72                      // padded LDS row stride (shorts), 144B = 9*16
#define WFRAG_MLP 24576              // 3 layers * 2 mats * 4096
#define WFRAG_TOT 26624              // + gate 2048
#define CONV1K ((NN * D) / 1024)     // 6250
#define WPREP1K (WFRAG_TOT / 1024)   // 26

typedef __attribute__((ext_vector_type(8))) short short8;            // 8 bf16 in 4 VGPRs
typedef __attribute__((ext_vector_type(8))) unsigned short ushort8;  // 16B row slice
typedef __attribute__((ext_vector_type(4))) float floatx4;           // MFMA accumulator

__device__ __forceinline__ unsigned short f2bf(float f) {
    unsigned int u = __float_as_uint(f);
    u += 0x7FFF + ((u >> 16) & 1);   // round-to-nearest-even
    return (unsigned short)(u >> 16);
}
__device__ __forceinline__ float bfu2f(unsigned short v) {
    return __uint_as_float(((unsigned int)v) << 16);
}

// ========== fused prep+partition: [part blocks | x->bf16 conv | weight frag] ==========
__global__ __launch_bounds__(1024) void k_prep_part(const float* __restrict__ x,
                                                    unsigned short* __restrict__ xb,
                                                    const float* __restrict__ W1,
                                                    const float* __restrict__ W2,
                                                    const float* __restrict__ gw1,
                                                    unsigned short* __restrict__ wfrag,
                                                    const int* __restrict__ src,
                                                    const int* __restrict__ dst,
                                                    int* __restrict__ bcur,
                                                    unsigned int* __restrict__ colbuf) {
    __shared__ int lcnt[NBK];
    __shared__ int lbase[NBK];
    int b = blockIdx.x;
    int tid = threadIdx.x;

    if (b < NPART) {
        int e0 = b * EPB;
        for (int i = tid; i < NBK; i += 1024) lcnt[i] = 0;
        __syncthreads();

        for (int e = tid; e < EPB; e += 1024)
            atomicAdd(&lcnt[dst[e0 + e] >> 8], 1);
        __syncthreads();

        for (int i = tid; i < NBK; i += 1024) {
            int c = lcnt[i];
            lbase[i] = c ? (i * CAP + atomicAdd(&bcur[i * 16], c)) : 0;
            lcnt[i] = 0;
        }
        __syncthreads();

        for (int e = tid; e < EPB; e += 1024) {
            int d = dst[e0 + e];
            int s = src[e0 + e];
            int bk = d >> 8;
            int pos = lbase[bk] + atomicAdd(&lcnt[bk], 1);
            colbuf[pos] = ((unsigned int)s << 8) | (unsigned int)(d & 255);
        }
    } else if (b < NPART + CONV1K) {
        int i = (b - NPART) * 1024 + tid;
        xb[i] = f2bf(x[i]);
    } else {
        int idx = (b - NPART - CONV1K) * 1024 + tid;
        if (idx < WFRAG_MLP) {
            int l = idx / 8192;
            int rem = idx % 8192;
            int mat = rem / 4096;
            int r2 = rem % 4096;
            int ks = r2 / 2048;
            int c = (r2 / 512) % 4;
            int lane = (r2 / 8) % 64;
            int j = r2 % 8;
            int n = lane & 15, q = lane >> 4;
            int k = ks * 32 + q * 8 + j;
            int col = c * 16 + n;
            const float* Wm = mat ? W2 : W1;
            wfrag[idx] = f2bf(Wm[l * 4096 + k * 64 + col]);
        } else {
            int g = idx - WFRAG_MLP;
            int ks = g / 1024;
            int c = (g / 512) % 2;
            int lane = (g / 8) % 64;
            int j = g % 8;
            int n = lane & 15, q = lane >> 4;
            int k = ks * 32 + q * 8 + j;
            wfrag[idx] = f2bf(gw1[k * 32 + c * 16 + n]);
        }
    }
}

// phase C: per-bucket histogram + scan -> row_start/row_end, then scatter col
// into a SEPARATE col buffer (no in-place hazard, no LDS staging).
__global__ __launch_bounds__(256) void k_bfill(const unsigned int* __restrict__ colbuf,
                                               const int* __restrict__ bcur,
                                               int* __restrict__ rps,
                                               int* __restrict__ rpe,
                                               int* __restrict__ col) {
    __shared__ int lcur[256];
    __shared__ int wsum[4];
    int b = blockIdx.x;
    int ebase = b * CAP;
    int cnt = bcur[b * 16];
    int nb0 = b * 256;
    int nodes = min(256, NN - nb0);
    int tid = threadIdx.x;
    int lane = tid & 63;
    int w = tid >> 6;

    lcur[tid] = 0;
    __syncthreads();

    for (int e = tid; e < cnt; e += 256)
        atomicAdd(&lcur[colbuf[ebase + e] & 255], 1);
    __syncthreads();

    int v = lcur[tid];
    int x = v;
#pragma unroll
    for (int off = 1; off < 64; off <<= 1) {
        int u = __shfl_up(x, off, 64);
        if (lane >= off) x += u;
    }
    if (lane == 63) wsum[w] = x;
    __syncthreads();
    int base = ebase;
    for (int k = 0; k < w; k++) base += wsum[k];
    int rp = base + x - v;
    if (tid < nodes) {
        rps[nb0 + tid] = rp;
        rpe[nb0 + tid] = rp + v;
    }
    lcur[tid] = rp;
    __syncthreads();

    for (int e = tid; e < cnt; e += 256) {
        unsigned int p = colbuf[ebase + e];
        int pos = atomicAdd(&lcur[p & 255], 1);
        col[pos] = p >> 8;
    }
}

// ================= gather: h = (1+eps)x + sum_neighbors (bf16 in/out) =================
// ONE WAVE PER NODE: 64 lanes = 8 edge-slots (j) x 8 feature-lanes (fl).
// Uniform loop bounds per wave (zero control divergence, no intra-wave degree convoy);
// 16 edges in flight per window; shfl_xor reduction over edge-slots at the end.
__global__ __launch_bounds__(256) void k_gather(const unsigned short* __restrict__ xin,
                                                unsigned short* __restrict__ h,
                                                const int* __restrict__ rps,
                                                const int* __restrict__ rpe,
                                                const int* __restrict__ col,
                                                const float* __restrict__ epsp) {
    int w = threadIdx.x >> 6;
    int lane = threadIdx.x & 63;
    int j = lane >> 3;      // edge slot 0..7
    int fl = lane & 7;      // 16B feature slice
    int node = blockIdx.x * 4 + w;
    int start = rps[node], end = rpe[node];
    float ev = 1.0f + *epsp;

    // self row (uniform across j; 8 distinct 16B loads per wave, broadcast)
    ushort8 xs = *(const ushort8*)(xin + ((size_t)node << 6) + fl * 8);

    float a0 = 0.f, a1 = 0.f, a2 = 0.f, a3 = 0.f, a4 = 0.f, a5 = 0.f, a6 = 0.f, a7 = 0.f;
    for (int eb = start; eb < end; eb += 16) {
        int e0 = eb + j;
        int e1 = eb + 8 + j;
        bool p0 = e0 < end;
        bool p1 = e1 < end;
        ushort8 r0, r1;
        if (p0) {
            int c0 = col[e0];
            r0 = *(const ushort8*)(xin + ((size_t)c0 << 6) + fl * 8);
        }
        if (p1) {
            int c1 = col[e1];
            r1 = *(const ushort8*)(xin + ((size_t)c1 << 6) + fl * 8);
        }
        if (p0) {
            a0 += bfu2f(r0[0]); a1 += bfu2f(r0[1]);
            a2 += bfu2f(r0[2]); a3 += bfu2f(r0[3]);
            a4 += bfu2f(r0[4]); a5 += bfu2f(r0[5]);
            a6 += bfu2f(r0[6]); a7 += bfu2f(r0[7]);
        }
        if (p1) {
            a0 += bfu2f(r1[0]); a1 += bfu2f(r1[1]);
            a2 += bfu2f(r1[2]); a3 += bfu2f(r1[3]);
            a4 += bfu2f(r1[4]); a5 += bfu2f(r1[5]);
            a6 += bfu2f(r1[6]); a7 += bfu2f(r1[7]);
        }
    }
    // reduce over the 8 edge slots (lanes with equal fl)
#pragma unroll
    for (int off = 8; off < 64; off <<= 1) {
        a0 += __shfl_xor(a0, off, 64);
        a1 += __shfl_xor(a1, off, 64);
        a2 += __shfl_xor(a2, off, 64);
        a3 += __shfl_xor(a3, off, 64);
        a4 += __shfl_xor(a4, off, 64);
        a5 += __shfl_xor(a5, off, 64);
        a6 += __shfl_xor(a6, off, 64);
        a7 += __shfl_xor(a7, off, 64);
    }
    if (j == 0) {
        ushort8 o;
        o[0] = f2bf(ev * bfu2f(xs[0]) + a0);
        o[1] = f2bf(ev * bfu2f(xs[1]) + a1);
        o[2] = f2bf(ev * bfu2f(xs[2]) + a2);
        o[3] = f2bf(ev * bfu2f(xs[3]) + a3);
        o[4] = f2bf(ev * bfu2f(xs[4]) + a4);
        o[5] = f2bf(ev * bfu2f(xs[5]) + a5);
        o[6] = f2bf(ev * bfu2f(xs[6]) + a6);
        o[7] = f2bf(ev * bfu2f(xs[7]) + a7);
        *(ushort8*)(h + ((size_t)node << 6) + fl * 8) = o;
    }
}

// ================= MFMA MLP + LN (+ fused gate on last layer) =================
// block = 4 waves = ONE 64-node tile (full grid for occupancy); wave owns 16 nodes.
template <int LAST>
__global__ __launch_bounds__(256) void k_mfma(const unsigned short* __restrict__ h,
                                              unsigned short* __restrict__ xout,
                                              const short8* __restrict__ wf,
                                              const short8* __restrict__ gf,
                                              const float* __restrict__ b1,
                                              const float* __restrict__ b2,
                                              const float* __restrict__ lng,
                                              const float* __restrict__ lnb,
                                              const float* __restrict__ gb1,
                                              const float* __restrict__ gw2,
                                              const float* __restrict__ gb2,
                                              float* __restrict__ gate) {
    __shared__ __align__(16) unsigned short a2[4][16 * LSTR];
    int w = threadIdx.x >> 6;
    int lane = threadIdx.x & 63;
    int n = lane & 15;
    int q = lane >> 4;
    int base = blockIdx.x * 64 + w * 16;

    short8 B1f[2][4], B2f[2][4];
#pragma unroll
    for (int ks = 0; ks < 2; ks++)
#pragma unroll
        for (int c = 0; c < 4; c++) {
            B1f[ks][c] = wf[(ks * 4 + c) * 64 + lane];
            B2f[ks][c] = wf[512 + (ks * 4 + c) * 64 + lane];
        }
    short8 B3f[2][2];
    if (LAST) {
#pragma unroll
        for (int ks = 0; ks < 2; ks++)
#pragma unroll
            for (int c = 0; c < 2; c++)
                B3f[ks][c] = gf[(ks * 2 + c) * 64 + lane];
    }

    float b1v[4], b2v[4], lgv[4], lbv[4];
#pragma unroll
    for (int c = 0; c < 4; c++) {
        b1v[c] = b1[c * 16 + n];
        b2v[c] = b2[c * 16 + n];
        lgv[c] = lng[c * 16 + n];
        lbv[c] = lnb[c * 16 + n];
    }
    float gb1v[2], gw2v[2], gb2v = 0.f;
    if (LAST) {
        gb1v[0] = gb1[n]; gb1v[1] = gb1[16 + n];
        gw2v[0] = gw2[n]; gw2v[1] = gw2[16 + n];
        gb2v = gb2[0];
    }

    unsigned short* aw = a2[w];

    int mnode = base + n;
    int mc = min(mnode, NN - 1);
    const short8* hp = (const short8*)(h + ((size_t)mc << 6));
    short8 A0 = hp[q];
    short8 A1 = hp[4 + q];

    floatx4 acc1[4];
#pragma unroll
    for (int c = 0; c < 4; c++) {
        floatx4 a = {b1v[c], b1v[c], b1v[c], b1v[c]};
        a = __builtin_amdgcn_mfma_f32_16x16x32_bf16(A0, B1f[0][c], a, 0, 0, 0);
        a = __builtin_amdgcn_mfma_f32_16x16x32_bf16(A1, B1f[1][c], a, 0, 0, 0);
        acc1[c] = a;
    }

#pragma unroll
    for (int c = 0; c < 4; c++)
#pragma unroll
        for (int r = 0; r < 4; r++) {
            float v = acc1[c][r];
            v = v / (1.0f + __expf(-v));
            aw[(q * 4 + r) * LSTR + c * 16 + n] = f2bf(v);
        }

    const short8* ap = (const short8*)(aw + n * LSTR);
    short8 A20 = ap[q];
    short8 A21 = ap[4 + q];

    floatx4 acc2[4];
#pragma unroll
    for (int c = 0; c < 4; c++) {
        floatx4 a = {b2v[c], b2v[c], b2v[c], b2v[c]};
        a = __builtin_amdgcn_mfma_f32_16x16x32_bf16(A20, B2f[0][c], a, 0, 0, 0);
        a = __builtin_amdgcn_mfma_f32_16x16x32_bf16(A21, B2f[1][c], a, 0, 0, 0);
        acc2[c] = a;
    }

    float mu[4], inv[4];
#pragma unroll
    for (int r = 0; r < 4; r++) {
        float s = acc2[0][r] + acc2[1][r] + acc2[2][r] + acc2[3][r];
#pragma unroll
        for (int off = 1; off < 16; off <<= 1) s += __shfl_xor(s, off, 64);
        mu[r] = s * (1.0f / 64.0f);
        float d0 = acc2[0][r] - mu[r], d1 = acc2[1][r] - mu[r];
        float d2 = acc2[2][r] - mu[r], d3 = acc2[3][r] - mu[r];
        float vv = d0 * d0 + d1 * d1 + d2 * d2 + d3 * d3;
#pragma unroll
        for (int off = 1; off < 16; off <<= 1) vv += __shfl_xor(vv, off, 64);
        inv[r] = rsqrtf(vv * (1.0f / 64.0f) + LN_EPS);
    }

#pragma unroll
    for (int c = 0; c < 4; c++)
#pragma unroll
        for (int r = 0; r < 4; r++) {
            int node = base + q * 4 + r;
            float o = (acc2[c][r] - mu[r]) * inv[r] * lgv[c] + lbv[c];
            unsigned short ob = f2bf(o);
            if (node < NN) xout[((size_t)node << 6) + c * 16 + n] = ob;
            if (LAST) aw[(q * 4 + r) * LSTR + c * 16 + n] = ob;
        }

    if (LAST) {
        short8 G0 = ap[q];
        short8 G1 = ap[4 + q];
        floatx4 acc3[2];
#pragma unroll
        for (int c = 0; c < 2; c++) {
            floatx4 a = {gb1v[c], gb1v[c], gb1v[c], gb1v[c]};
            a = __builtin_amdgcn_mfma_f32_16x16x32_bf16(G0, B3f[0][c], a, 0, 0, 0);
            a = __builtin_amdgcn_mfma_f32_16x16x32_bf16(G1, B3f[1][c], a, 0, 0, 0);
            acc3[c] = a;
        }
#pragma unroll
        for (int r = 0; r < 4; r++) {
            float v0 = acc3[0][r];
            v0 = v0 / (1.0f + __expf(-v0));
            float v1 = acc3[1][r];
            v1 = v1 / (1.0f + __expf(-v1));
            float gsum = v0 * gw2v[0] + v1 * gw2v[1];
#pragma unroll
            for (int off = 1; off < 16; off <<= 1) gsum += __shfl_xor(gsum, off, 64);
            int node = base + q * 4 + r;
            if (n == 0 && node < NN) gate[node] = gsum + gb2v;
        }
    }
}

// ================= per-graph softmax pooling =================
__global__ __launch_bounds__(256) void k_pool(const unsigned short* __restrict__ xf,
                                              const float* __restrict__ gate,
                                              const int* __restrict__ batch,
                                              float* __restrict__ out) {
    __shared__ float redm[4];
    __shared__ float reds[4];
    __shared__ float racc[4][D];
    int g = blockIdx.x;
    int w = threadIdx.x >> 6;
    int lane = threadIdx.x & 63;

    int lo = 0, hi = NN;
    while (lo < hi) { int mid = (lo + hi) >> 1; if (batch[mid] < g) lo = mid + 1; else hi = mid; }
    int start = lo;
    hi = NN;
    while (lo < hi) { int mid = (lo + hi) >> 1; if (batch[mid] < g + 1) lo = mid + 1; else hi = mid; }
    int end = lo;

    if (start >= end) {
        if (w == 0) out[((size_t)g << 6) + lane] = 0.0f;
        return;
    }

    float m = -INFINITY;
    for (int i = start + (int)threadIdx.x; i < end; i += 256) m = fmaxf(m, gate[i]);
#pragma unroll
    for (int mm = 32; mm >= 1; mm >>= 1) m = fmaxf(m, __shfl_xor(m, mm, 64));
    if (lane == 0) redm[w] = m;
    __syncthreads();
    m = fmaxf(fmaxf(redm[0], redm[1]), fmaxf(redm[2], redm[3]));

    float s = 0.0f;
    for (int i = start + (int)threadIdx.x; i < end; i += 256) s += __expf(gate[i] - m);
#pragma unroll
    for (int mm = 32; mm >= 1; mm >>= 1) s += __shfl_xor(s, mm, 64);
    if (lane == 0) reds[w] = s;
    __syncthreads();
    s = (reds[0] + reds[1]) + (reds[2] + reds[3]);

    float acc = 0.0f;
    for (int i = start + w; i < end; i += 4)
        acc += __expf(gate[i] - m) * bfu2f(xf[((size_t)i << 6) + lane]);
    racc[w][lane] = acc;
    __syncthreads();
    if (w == 0)
        out[((size_t)g << 6) + lane] =
            ((racc[0][lane] + racc[1][lane]) + (racc[2][lane] + racc[3][lane])) / s;
}

extern "C" void kernel_launch(void* const* d_in, const int* in_sizes, int n_in,
                              void* d_out, int out_size, void* d_ws, size_t ws_size,
                              hipStream_t stream) {
    const float* x   = (const float*)d_in[0];
    const int* ei    = (const int*)d_in[1];
    const int* batch = (const int*)d_in[2];
    const float* W1  = (const float*)d_in[3];
    const float* b1  = (const float*)d_in[4];
    const float* W2  = (const float*)d_in[5];
    const float* b2  = (const float*)d_in[6];
    const float* eps = (const float*)d_in[7];
    const float* lng = (const float*)d_in[8];
    const float* lnb = (const float*)d_in[9];
    const float* gw1 = (const float*)d_in[10];
    const float* gb1 = (const float*)d_in[11];
    const float* gw2 = (const float*)d_in[12];
    const float* gb2 = (const float*)d_in[13];

    const int* src = ei;
    const int* dst = ei + NE;

    // workspace layout (~46 MB)
    unsigned short* xb    = (unsigned short*)d_ws;              // NN*64 bf16 (ping)
    unsigned short* h     = xb + (size_t)NN * D;                // NN*64 bf16 (pong)
    float* gate           = (float*)(h + (size_t)NN * D);       // NN f32
    int* rps              = (int*)(gate + NN);                  // NN
    int* rpe              = rps + NN;                           // NN
    int* colbuf           = rpe + NN;                           // NBK*CAP (bucketed, tagged)
    int* col              = colbuf + (size_t)NBK * CAP;         // NBK*CAP (node-sorted)
    int* bcur             = col + (size_t)NBK * CAP;            // NBK*16 counts
    unsigned short* wfrag = (unsigned short*)(bcur + NBK * 16); // WFRAG_TOT

    float* out = (float*)d_out;

    // ---- CSR build + prep (overlapped in one kernel; bcur = counts, memset 0) ----
    hipMemsetAsync(bcur, 0, NBK * 16 * sizeof(int), stream);
    k_prep_part<<<NPART + CONV1K + WPREP1K, 1024, 0, stream>>>(
        x, xb, W1, W2, gw1, wfrag, src, dst, bcur, (unsigned int*)colbuf);
    k_bfill<<<NBK, 256, 0, stream>>>((unsigned int*)colbuf, bcur, rps, rpe, col);

    const short8* wf0 = (const short8*)(wfrag);
    const short8* wf1 = (const short8*)(wfrag + 8192);
    const short8* wf2 = (const short8*)(wfrag + 16384);
    const short8* gf  = (const short8*)(wfrag + WFRAG_MLP);

    // ---- 3 GIN layers (wave-per-node gather: no degree convoy; split mfma) ----
    k_gather<<<NN / 4, 256, 0, stream>>>(xb, h, rps, rpe, col, eps + 0);
    k_mfma<0><<<NTILE, 256, 0, stream>>>(h, xb, wf0, gf,
        b1 + 0 * D, b2 + 0 * D, lng + 0 * D, lnb + 0 * D, gb1, gw2, gb2, gate);

    k_gather<<<NN / 4, 256, 0, stream>>>(xb, h, rps, rpe, col, eps + 1);
    k_mfma<0><<<NTILE, 256, 0, stream>>>(h, xb, wf1, gf,
        b1 + 1 * D, b2 + 1 * D, lng + 1 * D, lnb + 1 * D, gb1, gw2, gb2, gate);

    k_gather<<<NN / 4, 256, 0, stream>>>(xb, h, rps, rpe, col, eps + 2);
    k_mfma<1><<<NTILE, 256, 0, stream>>>(h, xb, wf2, gf,
        b1 + 2 * D, b2 + 2 * D, lng + 2 * D, lnb + 2 * D, gb1, gw2, gb2, gate);

    k_pool<<<NG, 256, 0, stream>>>(xb, gate, batch, out);
}

// Round 8
// 283.331 us; speedup vs baseline: 7.7021x; 1.1714x over previous
//
#include <hip/hip_runtime.h>
#include <math.h>

#define NN 100000
#define NE 1600000
#define D 64
#define NG 2000
#define LN_EPS 1e-5f
#define NB ((NN + 255) / 256)        // 391 buckets of 256 nodes
#define NBK NB
#define NTILE ((NN + 63) / 64)       // 1563
#define EPB 6400                     // edges per partition block (250 blocks)
#define NPART (NE / EPB)             // 250
#define CAP 6144                     // bucket capacity (expected 4096, ~32 sigma slack)
#define LSTR 72                      // padded LDS row stride (shorts), 144B = 9*16
#define WFRAG_MLP 24576              // 3 layers * 2 mats * 4096
#define WFRAG_TOT 26624              // + gate 2048
#define CONV1K ((NN * D) / 1024)     // 6250
#define WPREP1K (WFRAG_TOT / 1024)   // 26

typedef __attribute__((ext_vector_type(8))) short short8;            // 8 bf16 in 4 VGPRs
typedef __attribute__((ext_vector_type(8))) unsigned short ushort8;  // 16B row slice
typedef __attribute__((ext_vector_type(4))) float floatx4;           // MFMA accumulator

__device__ __forceinline__ unsigned short f2bf(float f) {
    unsigned int u = __float_as_uint(f);
    u += 0x7FFF + ((u >> 16) & 1);   // round-to-nearest-even
    return (unsigned short)(u >> 16);
}
__device__ __forceinline__ float bfu2f(unsigned short v) {
    return __uint_as_float(((unsigned int)v) << 16);
}

// ========== fused prep+partition: [part blocks | x->bf16 conv | weight frag] ==========
__global__ __launch_bounds__(1024) void k_prep_part(const float* __restrict__ x,
                                                    unsigned short* __restrict__ xb,
                                                    const float* __restrict__ W1,
                                                    const float* __restrict__ W2,
                                                    const float* __restrict__ gw1,
                                                    unsigned short* __restrict__ wfrag,
                                                    const int* __restrict__ src,
                                                    const int* __restrict__ dst,
                                                    int* __restrict__ bcur,
                                                    unsigned int* __restrict__ colbuf) {
    __shared__ int lcnt[NBK];
    __shared__ int lbase[NBK];
    int b = blockIdx.x;
    int tid = threadIdx.x;

    if (b < NPART) {
        int e0 = b * EPB;
        for (int i = tid; i < NBK; i += 1024) lcnt[i] = 0;
        __syncthreads();

        for (int e = tid; e < EPB; e += 1024)
            atomicAdd(&lcnt[dst[e0 + e] >> 8], 1);
        __syncthreads();

        for (int i = tid; i < NBK; i += 1024) {
            int c = lcnt[i];
            lbase[i] = c ? (i * CAP + atomicAdd(&bcur[i * 16], c)) : 0;
            lcnt[i] = 0;
        }
        __syncthreads();

        for (int e = tid; e < EPB; e += 1024) {
            int d = dst[e0 + e];
            int s = src[e0 + e];
            int bk = d >> 8;
            int pos = lbase[bk] + atomicAdd(&lcnt[bk], 1);
            colbuf[pos] = ((unsigned int)s << 8) | (unsigned int)(d & 255);
        }
    } else if (b < NPART + CONV1K) {
        int i = (b - NPART) * 1024 + tid;
        xb[i] = f2bf(x[i]);
    } else {
        int idx = (b - NPART - CONV1K) * 1024 + tid;
        if (idx < WFRAG_MLP) {
            int l = idx / 8192;
            int rem = idx % 8192;
            int mat = rem / 4096;
            int r2 = rem % 4096;
            int ks = r2 / 2048;
            int c = (r2 / 512) % 4;
            int lane = (r2 / 8) % 64;
            int j = r2 % 8;
            int n = lane & 15, q = lane >> 4;
            int k = ks * 32 + q * 8 + j;
            int col = c * 16 + n;
            const float* Wm = mat ? W2 : W1;
            wfrag[idx] = f2bf(Wm[l * 4096 + k * 64 + col]);
        } else {
            int g = idx - WFRAG_MLP;
            int ks = g / 1024;
            int c = (g / 512) % 2;
            int lane = (g / 8) % 64;
            int j = g % 8;
            int n = lane & 15, q = lane >> 4;
            int k = ks * 32 + q * 8 + j;
            wfrag[idx] = f2bf(gw1[k * 32 + c * 16 + n]);
        }
    }
}

// phase C: per-bucket histogram + scan -> row_start/row_end, then scatter col
// into a SEPARATE col buffer (no in-place hazard, no LDS staging).
__global__ __launch_bounds__(256) void k_bfill(const unsigned int* __restrict__ colbuf,
                                               const int* __restrict__ bcur,
                                               int* __restrict__ rps,
                                               int* __restrict__ rpe,
                                               int* __restrict__ col) {
    __shared__ int lcur[256];
    __shared__ int wsum[4];
    int b = blockIdx.x;
    int ebase = b * CAP;
    int cnt = bcur[b * 16];
    int nb0 = b * 256;
    int nodes = min(256, NN - nb0);
    int tid = threadIdx.x;
    int lane = tid & 63;
    int w = tid >> 6;

    lcur[tid] = 0;
    __syncthreads();

    for (int e = tid; e < cnt; e += 256)
        atomicAdd(&lcur[colbuf[ebase + e] & 255], 1);
    __syncthreads();

    int v = lcur[tid];
    int x = v;
#pragma unroll
    for (int off = 1; off < 64; off <<= 1) {
        int u = __shfl_up(x, off, 64);
        if (lane >= off) x += u;
    }
    if (lane == 63) wsum[w] = x;
    __syncthreads();
    int base = ebase;
    for (int k = 0; k < w; k++) base += wsum[k];
    int rp = base + x - v;
    if (tid < nodes) {
        rps[nb0 + tid] = rp;
        rpe[nb0 + tid] = rp + v;
    }
    lcur[tid] = rp;
    __syncthreads();

    for (int e = tid; e < cnt; e += 256) {
        unsigned int p = colbuf[ebase + e];
        int pos = atomicAdd(&lcur[p & 255], 1);
        col[pos] = p >> 8;
    }
}

// ========== fully wave-private fused layer: gather(16 nodes/wave) + MFMA + LN(+gate) ====
// Wave = 16 nodes for BOTH phases: gather uses 4 lanes/node x 32B/lane (window of 4
// edges -> 8x16B loads in flight per lane), writes rows to the wave's private LDS
// region, then runs its own 16-node MFMA tile. ZERO barriers, zero idle waves,
// no global h traffic.
template <int LAST>
__global__ __launch_bounds__(256) void k_layer(const unsigned short* __restrict__ xin,
                                               unsigned short* __restrict__ xout,
                                               const int* __restrict__ rps,
                                               const int* __restrict__ rpe,
                                               const int* __restrict__ col,
                                               const float* __restrict__ epsp,
                                               const short8* __restrict__ wf,
                                               const short8* __restrict__ gf,
                                               const float* __restrict__ b1,
                                               const float* __restrict__ b2,
                                               const float* __restrict__ lng,
                                               const float* __restrict__ lnb,
                                               const float* __restrict__ gb1,
                                               const float* __restrict__ gw2,
                                               const float* __restrict__ gb2,
                                               float* __restrict__ gate) {
    __shared__ __align__(16) unsigned short smH[4][16 * LSTR];  // gathered rows
    __shared__ __align__(16) unsigned short smA[4][16 * LSTR];  // post-SiLU transpose
    int w = threadIdx.x >> 6;
    int lane = threadIdx.x & 63;
    int n = lane & 15;        // node within wave tile
    int fl = lane >> 4;       // feature quarter 0..3 (32B slice)
    int base = blockIdx.x * 64 + w * 16;
    int node = base + n;
    int nc = min(node, NN - 1);
    int st = rps[nc];
    int en = (node < NN) ? rpe[nc] : st;
    float ev = 1.0f + *epsp;

    // ---- gather phase (wave-private) ----
    float a[16];
#pragma unroll
    for (int e = 0; e < 16; e++) a[e] = 0.f;

    // uniform window count across the wave (max over its 16 nodes)
    int nwin = (en - st + 3) >> 2;
#pragma unroll
    for (int off = 1; off < 64; off <<= 1) nwin = max(nwin, __shfl_xor(nwin, off, 64));

    const unsigned short* xrow = xin + ((size_t)nc << 6) + fl * 16;
    ushort8 xs0 = *(const ushort8*)(xrow);
    ushort8 xs1 = *(const ushort8*)(xrow + 8);

    for (int t = 0; t < nwin; t++) {
        int b0 = st + t * 4;
        int ce = b0 + fl;                       // this lane carries edge (t*4+fl) of node n
        int c0 = (ce < en) ? col[ce] : -1;
        ushort8 v0[4], v1[4];
        unsigned int m = 0;
#pragma unroll
        for (int j = 0; j < 4; j++) {
            int idx = __shfl(c0, n + j * 16, 64);
            if (idx >= 0) {
                const ushort8* p = (const ushort8*)(xin + ((size_t)idx << 6) + fl * 16);
                v0[j] = p[0];
                v1[j] = p[1];
                m |= 1u << j;
            }
        }
#pragma unroll
        for (int j = 0; j < 4; j++)
            if (m & (1u << j)) {
#pragma unroll
                for (int e = 0; e < 8; e++) {
                    a[e] += bfu2f(v0[j][e]);
                    a[8 + e] += bfu2f(v1[j][e]);
                }
            }
    }

    {
        ushort8 o0, o1;
#pragma unroll
        for (int e = 0; e < 8; e++) {
            o0[e] = f2bf(ev * bfu2f(xs0[e]) + a[e]);
            o1[e] = f2bf(ev * bfu2f(xs1[e]) + a[8 + e]);
        }
        unsigned short* hw = smH[w] + n * LSTR + fl * 16;
        *(ushort8*)(hw) = o0;
        *(ushort8*)(hw + 8) = o1;
    }
    // no __syncthreads: wave reads only its own LDS region (compiler inserts lgkmcnt)

    // ---- MFMA MLP + LN phase (same wave, q == fl) ----
    int q = fl;

    short8 B1f[2][4], B2f[2][4];
#pragma unroll
    for (int ks = 0; ks < 2; ks++)
#pragma unroll
        for (int c = 0; c < 4; c++) {
            B1f[ks][c] = wf[(ks * 4 + c) * 64 + lane];
            B2f[ks][c] = wf[512 + (ks * 4 + c) * 64 + lane];
        }
    short8 B3f[2][2];
    if (LAST) {
#pragma unroll
        for (int ks = 0; ks < 2; ks++)
#pragma unroll
            for (int c = 0; c < 2; c++)
                B3f[ks][c] = gf[(ks * 2 + c) * 64 + lane];
    }

    float b1v[4], b2v[4], lgv[4], lbv[4];
#pragma unroll
    for (int c = 0; c < 4; c++) {
        b1v[c] = b1[c * 16 + n];
        b2v[c] = b2[c * 16 + n];
        lgv[c] = lng[c * 16 + n];
        lbv[c] = lnb[c * 16 + n];
    }
    float gb1v[2], gw2v[2], gb2v = 0.f;
    if (LAST) {
        gb1v[0] = gb1[n]; gb1v[1] = gb1[16 + n];
        gw2v[0] = gw2[n]; gw2v[1] = gw2[16 + n];
        gb2v = gb2[0];
    }

    unsigned short* aw = smA[w];

    const short8* hp = (const short8*)(smH[w] + n * LSTR);
    short8 A0 = hp[q];
    short8 A1 = hp[4 + q];

    floatx4 acc1[4];
#pragma unroll
    for (int c = 0; c < 4; c++) {
        floatx4 a1 = {b1v[c], b1v[c], b1v[c], b1v[c]};
        a1 = __builtin_amdgcn_mfma_f32_16x16x32_bf16(A0, B1f[0][c], a1, 0, 0, 0);
        a1 = __builtin_amdgcn_mfma_f32_16x16x32_bf16(A1, B1f[1][c], a1, 0, 0, 0);
        acc1[c] = a1;
    }

#pragma unroll
    for (int c = 0; c < 4; c++)
#pragma unroll
        for (int r = 0; r < 4; r++) {
            float v = acc1[c][r];
            v = v / (1.0f + __expf(-v));
            aw[(q * 4 + r) * LSTR + c * 16 + n] = f2bf(v);
        }

    const short8* ap = (const short8*)(aw + n * LSTR);
    short8 A20 = ap[q];
    short8 A21 = ap[4 + q];

    floatx4 acc2[4];
#pragma unroll
    for (int c = 0; c < 4; c++) {
        floatx4 a2 = {b2v[c], b2v[c], b2v[c], b2v[c]};
        a2 = __builtin_amdgcn_mfma_f32_16x16x32_bf16(A20, B2f[0][c], a2, 0, 0, 0);
        a2 = __builtin_amdgcn_mfma_f32_16x16x32_bf16(A21, B2f[1][c], a2, 0, 0, 0);
        acc2[c] = a2;
    }

    float mu[4], inv[4];
#pragma unroll
    for (int r = 0; r < 4; r++) {
        float s = acc2[0][r] + acc2[1][r] + acc2[2][r] + acc2[3][r];
#pragma unroll
        for (int off = 1; off < 16; off <<= 1) s += __shfl_xor(s, off, 64);
        mu[r] = s * (1.0f / 64.0f);
        float d0 = acc2[0][r] - mu[r], d1 = acc2[1][r] - mu[r];
        float d2 = acc2[2][r] - mu[r], d3 = acc2[3][r] - mu[r];
        float vv = d0 * d0 + d1 * d1 + d2 * d2 + d3 * d3;
#pragma unroll
        for (int off = 1; off < 16; off <<= 1) vv += __shfl_xor(vv, off, 64);
        inv[r] = rsqrtf(vv * (1.0f / 64.0f) + LN_EPS);
    }

#pragma unroll
    for (int c = 0; c < 4; c++)
#pragma unroll
        for (int r = 0; r < 4; r++) {
            int onode = base + q * 4 + r;
            float o = (acc2[c][r] - mu[r]) * inv[r] * lgv[c] + lbv[c];
            unsigned short ob = f2bf(o);
            if (onode < NN) xout[((size_t)onode << 6) + c * 16 + n] = ob;
            if (LAST) aw[(q * 4 + r) * LSTR + c * 16 + n] = ob;
        }

    if (LAST) {
        short8 G0 = ap[q];
        short8 G1 = ap[4 + q];
        floatx4 acc3[2];
#pragma unroll
        for (int c = 0; c < 2; c++) {
            floatx4 a3 = {gb1v[c], gb1v[c], gb1v[c], gb1v[c]};
            a3 = __builtin_amdgcn_mfma_f32_16x16x32_bf16(G0, B3f[0][c], a3, 0, 0, 0);
            a3 = __builtin_amdgcn_mfma_f32_16x16x32_bf16(G1, B3f[1][c], a3, 0, 0, 0);
            acc3[c] = a3;
        }
#pragma unroll
        for (int r = 0; r < 4; r++) {
            float v0 = acc3[0][r];
            v0 = v0 / (1.0f + __expf(-v0));
            float v1 = acc3[1][r];
            v1 = v1 / (1.0f + __expf(-v1));
            float gsum = v0 * gw2v[0] + v1 * gw2v[1];
#pragma unroll
            for (int off = 1; off < 16; off <<= 1) gsum += __shfl_xor(gsum, off, 64);
            int onode = base + q * 4 + r;
            if (n == 0 && onode < NN) gate[onode] = gsum + gb2v;
        }
    }
}

// ================= per-graph softmax pooling =================
__global__ __launch_bounds__(256) void k_pool(const unsigned short* __restrict__ xf,
                                              const float* __restrict__ gate,
                                              const int* __restrict__ batch,
                                              float* __restrict__ out) {
    __shared__ float redm[4];
    __shared__ float reds[4];
    __shared__ float racc[4][D];
    int g = blockIdx.x;
    int w = threadIdx.x >> 6;
    int lane = threadIdx.x & 63;

    int lo = 0, hi = NN;
    while (lo < hi) { int mid = (lo + hi) >> 1; if (batch[mid] < g) lo = mid + 1; else hi = mid; }
    int start = lo;
    hi = NN;
    while (lo < hi) { int mid = (lo + hi) >> 1; if (batch[mid] < g + 1) lo = mid + 1; else hi = mid; }
    int end = lo;

    if (start >= end) {
        if (w == 0) out[((size_t)g << 6) + lane] = 0.0f;
        return;
    }

    float m = -INFINITY;
    for (int i = start + (int)threadIdx.x; i < end; i += 256) m = fmaxf(m, gate[i]);
#pragma unroll
    for (int mm = 32; mm >= 1; mm >>= 1) m = fmaxf(m, __shfl_xor(m, mm, 64));
    if (lane == 0) redm[w] = m;
    __syncthreads();
    m = fmaxf(fmaxf(redm[0], redm[1]), fmaxf(redm[2], redm[3]));

    float s = 0.0f;
    for (int i = start + (int)threadIdx.x; i < end; i += 256) s += __expf(gate[i] - m);
#pragma unroll
    for (int mm = 32; mm >= 1; mm >>= 1) s += __shfl_xor(s, mm, 64);
    if (lane == 0) reds[w] = s;
    __syncthreads();
    s = (reds[0] + reds[1]) + (reds[2] + reds[3]);

    float acc = 0.0f;
    for (int i = start + w; i < end; i += 4)
        acc += __expf(gate[i] - m) * bfu2f(xf[((size_t)i << 6) + lane]);
    racc[w][lane] = acc;
    __syncthreads();
    if (w == 0)
        out[((size_t)g << 6) + lane] =
            ((racc[0][lane] + racc[1][lane]) + (racc[2][lane] + racc[3][lane])) / s;
}

extern "C" void kernel_launch(void* const* d_in, const int* in_sizes, int n_in,
                              void* d_out, int out_size, void* d_ws, size_t ws_size,
                              hipStream_t stream) {
    const float* x   = (const float*)d_in[0];
    const int* ei    = (const int*)d_in[1];
    const int* batch = (const int*)d_in[2];
    const float* W1  = (const float*)d_in[3];
    const float* b1  = (const float*)d_in[4];
    const float* W2  = (const float*)d_in[5];
    const float* b2  = (const float*)d_in[6];
    const float* eps = (const float*)d_in[7];
    const float* lng = (const float*)d_in[8];
    const float* lnb = (const float*)d_in[9];
    const float* gw1 = (const float*)d_in[10];
    const float* gb1 = (const float*)d_in[11];
    const float* gw2 = (const float*)d_in[12];
    const float* gb2 = (const float*)d_in[13];

    const int* src = ei;
    const int* dst = ei + NE;

    // workspace layout (~46 MB)
    unsigned short* xb    = (unsigned short*)d_ws;              // NN*64 bf16 (ping)
    unsigned short* h     = xb + (size_t)NN * D;                // NN*64 bf16 (pong)
    float* gate           = (float*)(h + (size_t)NN * D);       // NN f32
    int* rps              = (int*)(gate + NN);                  // NN
    int* rpe              = rps + NN;                           // NN
    int* colbuf           = rpe + NN;                           // NBK*CAP (bucketed, tagged)
    int* col              = colbuf + (size_t)NBK * CAP;         // NBK*CAP (node-sorted)
    int* bcur             = col + (size_t)NBK * CAP;            // NBK*16 counts
    unsigned short* wfrag = (unsigned short*)(bcur + NBK * 16); // WFRAG_TOT

    float* out = (float*)d_out;

    // ---- CSR build + prep ----
    hipMemsetAsync(bcur, 0, NBK * 16 * sizeof(int), stream);
    k_prep_part<<<NPART + CONV1K + WPREP1K, 1024, 0, stream>>>(
        x, xb, W1, W2, gw1, wfrag, src, dst, bcur, (unsigned int*)colbuf);
    k_bfill<<<NBK, 256, 0, stream>>>((unsigned int*)colbuf, bcur, rps, rpe, col);

    const short8* wf0 = (const short8*)(wfrag);
    const short8* wf1 = (const short8*)(wfrag + 8192);
    const short8* wf2 = (const short8*)(wfrag + 16384);
    const short8* gf  = (const short8*)(wfrag + WFRAG_MLP);

    // ---- 3 fused GIN layers (wave-private: no barriers, no idle waves) ----
    k_layer<0><<<NTILE, 256, 0, stream>>>(xb, h, rps, rpe, col, eps + 0, wf0, gf,
        b1 + 0 * D, b2 + 0 * D, lng + 0 * D, lnb + 0 * D, gb1, gw2, gb2, gate);

    k_layer<0><<<NTILE, 256, 0, stream>>>(h, xb, rps, rpe, col, eps + 1, wf1, gf,
        b1 + 1 * D, b2 + 1 * D, lng + 1 * D, lnb + 1 * D, gb1, gw2, gb2, gate);

    k_layer<1><<<NTILE, 256, 0, stream>>>(xb, h, rps, rpe, col, eps + 2, wf2, gf,
        b1 + 2 * D, b2 + 2 * D, lng + 2 * D, lnb + 2 * D, gb1, gw2, gb2, gate);

    k_pool<<<NG, 256, 0, stream>>>(h, gate, batch, out);
}